// Round 5
// baseline (2694.076 us; speedup 1.0000x reference)
//
#include <hip/hip_runtime.h>

constexpr int NN = 50000;
constexpr int EE = 800000;
constexpr int HH = 128;

typedef __attribute__((ext_vector_type(8))) __bf16 bfv8;
typedef __attribute__((ext_vector_type(4))) float f32x4;
typedef unsigned short u16;

__device__ __forceinline__ u16 f2bf(float x){
  unsigned u = __builtin_bit_cast(unsigned, x);
  u = u + 0x7fffu + ((u >> 16) & 1u);
  return (u16)(u >> 16);
}
// fast silu: v_rcp instead of precise-div sequence (no fast-math in harness)
__device__ __forceinline__ float fsilu(float x){
  return x * __builtin_amdgcn_rcpf(1.f + __expf(-x));
}

// A is LDS, row-major RB bytes/row; if SWZ, element byte col c stored at c ^ ((row&7)<<4).
// B is packed fragment-order global: frag unit index (ks*CB+cb)*64 + lane, 8 bf16 each.
// INIT=false: accumulate into caller's acc (bias ignored).
template<int KSTEPS, int CB, int RB, bool INIT, bool SWZ>
__device__ __forceinline__ void mm_tile(const u16* A, int Rbase, const u16* __restrict__ Bp,
                                        const float* __restrict__ bias, int NB, f32x4* acc){
  const int lane = threadIdx.x & 63;
  if constexpr (INIT){
    #pragma unroll
    for (int cb = 0; cb < CB; ++cb){
      int col = cb*16 + (lane & 15);
      float b = (col < NB) ? bias[col] : 0.f;
      acc[cb] = (f32x4){b, b, b, b};
    }
  }
  const int arow = Rbase + (lane & 15);
  const char* abase = (const char*)A + arow * RB;
  const int kb = (lane >> 4) * 16;          // byte offset of this lane-group's 8 k-elems
  const int swz = SWZ ? ((arow & 7) << 4) : 0;
  const bfv8* __restrict__ bq = (const bfv8*)Bp + lane;
  __builtin_amdgcn_s_setprio(1);
  for (int ks = 0; ks < KSTEPS; ++ks){
    bfv8 a = *(const bfv8*)(abase + ((ks*64 + kb) ^ swz));
    #pragma unroll
    for (int cb = 0; cb < CB; ++cb){
      bfv8 b = bq[(ks*CB + cb) * 64];
      acc[cb] = __builtin_amdgcn_mfma_f32_16x16x32_bf16(a, b, acc[cb], 0, 0, 0);
    }
  }
  __builtin_amdgcn_s_setprio(0);
}

// silu(acc) -> bf16 into LDS (256B rows, swizzled)
template<int CB>
__device__ __forceinline__ void silu_store(const f32x4* acc, u16* dst, int Rbase){
  const int lane = threadIdx.x & 63;
  #pragma unroll
  for (int cb = 0; cb < CB; ++cb){
    #pragma unroll
    for (int j = 0; j < 4; ++j){
      int row = Rbase + ((lane >> 4) << 2) + j;
      int col = cb*16 + (lane & 15);
      float s = fsilu(acc[cb][j]);
      *(u16*)((char*)dst + row*256 + ((col*2) ^ ((row & 7) << 4))) = f2bf(s);
    }
  }
}

// ---------------- weight packing ----------------
// remap==1 (ew1): packed k order is [h(256) | ef(16) | nrm | pad(15)]
// while source ew1 rows are [h(256) | nrm@256 | ef@257..272].
struct PackDesc { const float* src; u16* dst; int K; int Nc; int CB; int ksteps; int remap; };
struct PackArgs { PackDesc d[32]; };

__global__ __launch_bounds__(256) void pack_kernel(PackArgs pa){
  PackDesc d = pa.d[blockIdx.x];
  int total = d.ksteps * d.CB * 512;
  for (int p = threadIdx.x; p < total; p += 256){
    int j = p & 7, lane = (p >> 3) & 63, cbk = p >> 9;
    int cb = cbk % d.CB, ks = cbk / d.CB;
    int k = ks*32 + ((lane >> 4) * 8) + j;
    int col = cb*16 + (lane & 15);
    int kk = k;
    if (d.remap && k >= 256) kk = (k < 272) ? (k + 1) : ((k == 272) ? 256 : 0x7fffffff);
    float v = (kk < d.K && col < d.Nc) ? d.src[(size_t)kk * d.Nc + col] : 0.f;
    d.dst[p] = f2bf(v);
  }
}

// ---------------- embedding + coords init ----------------
__global__ __launch_bounds__(256) void embed_kernel(const float* __restrict__ nodes,
    const float* __restrict__ emb_w, const float* __restrict__ emb_b,
    float* __restrict__ hf, u16* __restrict__ hbf, float* __restrict__ coords){
  int t = blockIdx.x * 256 + threadIdx.x;
  int g = t >> 2, q = t & 3;
  if (g >= NN) return;
  const float* x = nodes + (size_t)g * 22;
  float acc[32];
  #pragma unroll
  for (int c = 0; c < 32; ++c) acc[c] = emb_b[q*32 + c];
  for (int k = 0; k < 16; ++k){
    float f = x[6 + k];
    const float* wr = emb_w + k*128 + q*32;
    #pragma unroll
    for (int c = 0; c < 32; ++c) acc[c] += f * wr[c];
  }
  size_t off = (size_t)g * HH + q*32;
  #pragma unroll
  for (int c = 0; c < 32; ++c){ hf[off + c] = acc[c]; hbf[off + c] = f2bf(acc[c]); }
  if (q == 0){
    coords[g*3+0] = x[0]; coords[g*3+1] = x[1]; coords[g*3+2] = x[2];
  }
}

// ---------------- CSR build (once per launch) ----------------
__global__ __launch_bounds__(256) void count_kernel(const int* __restrict__ esrc, int* __restrict__ cnt_i){
  int e = blockIdx.x * 256 + threadIdx.x;
  if (e < EE) atomicAdd(&cnt_i[esrc[e]], 1);
}

__global__ __launch_bounds__(256) void scan_kernel(const int* __restrict__ cnt_i,
    int* __restrict__ row_start, int* __restrict__ fill){
  __shared__ int part[256];
  int t = threadIdx.x;
  int lo = t * 196, hi = lo + 196;
  if (lo > NN) lo = NN;
  if (hi > NN) hi = NN;
  int s = 0;
  for (int i = lo; i < hi; ++i) s += cnt_i[i];
  part[t] = s; __syncthreads();
  for (int d = 1; d < 256; d <<= 1){
    int v = (t >= d) ? part[t-d] : 0;
    __syncthreads();
    part[t] += v;
    __syncthreads();
  }
  int run = part[t] - s;             // exclusive prefix
  for (int i = lo; i < hi; ++i){ row_start[i] = run; fill[i] = run; run += cnt_i[i]; }
  if (t == 255) row_start[NN] = run;
}

__global__ __launch_bounds__(256) void scatter_kernel(const int* __restrict__ esrc,
    const int* __restrict__ edst, int* __restrict__ fill,
    int2* __restrict__ sd_sorted, int* __restrict__ eid_sorted){
  int e = blockIdx.x * 256 + threadIdx.x;
  if (e < EE){
    int s = esrc[e];
    int pos = atomicAdd(&fill[s], 1);
    sd_sorted[pos] = make_int2(s, edst[e]);
    eid_sorted[pos] = e;
  }
}

// ---------------- edge kernel ----------------
// 64 sorted edges/block, 4 independent waves x 16 rows (no __syncthreads).
// X split into three tiles to fit 4 blocks/CU:
//   X_hs[64][128] (256B rows, swz), X_hd[64][128] (256B rows, swz),
//   X_tail[64][32] (64B rows, no swz; cols = [ef(16)|nrm|pad]).
// ew1 GEMM = 3 accumulating mm_tile calls (K = 128+128+32).
// Wave scratch M1/Mb alias the wave's own 16 rows of X_hs/X_hd (dead after ew1).
__global__ __launch_bounds__(256) void edge_kernel(
    const float* __restrict__ coords, const u16* __restrict__ hbf, const float* __restrict__ ef,
    const int2* __restrict__ sd_sorted, const int* __restrict__ eid_sorted,
    const u16* __restrict__ ew1p, const u16* __restrict__ ew2p,
    const u16* __restrict__ cw1p, const u16* __restrict__ cw2p,
    const float* __restrict__ eb1, const float* __restrict__ eb2,
    const float* __restrict__ cb1, const float* __restrict__ cb2,
    float* __restrict__ agg, float* __restrict__ acc_ct){
  __shared__ __align__(16) u16 sXhs[64 * 128];
  __shared__ __align__(16) u16 sXhd[64 * 128];
  __shared__ __align__(16) u16 sXtail[64 * 32];
  __shared__ float4 s_cdn[64];
  __shared__ int s_src[64];
  __shared__ int s_dst[64];
  __shared__ int s_eid[64];

  const int tid = threadIdx.x, wid = tid >> 6, lane = tid & 63;
  const int R = wid * 16;
  const int e0 = blockIdx.x * 64;

  // Phase A: per-edge scalars (each wave fills its own 16 rows)
  if (lane < 16){
    int row = R + lane;
    int e = e0 + row;
    int2 sd = sd_sorted[e];
    float cx = coords[sd.x*3+0] - coords[sd.y*3+0];
    float cy = coords[sd.x*3+1] - coords[sd.y*3+1];
    float cz = coords[sd.x*3+2] - coords[sd.y*3+2];
    float nrm = sqrtf(cx*cx + cy*cy + cz*cz);
    s_cdn[row] = make_float4(cx, cy, cz, nrm);
    s_src[row] = sd.x; s_dst[row] = sd.y; s_eid[row] = eid_sorted[e];
  }
  // Phase B: stage X tiles, wave-uniform region per iteration (4 lanes/row)
  {
    int row = R + (lane >> 2), q = lane & 3;
    int s = s_src[row], d = s_dst[row], eid = s_eid[row];
    const uint4* hs = (const uint4*)(hbf + (size_t)s * HH);
    const uint4* hd = (const uint4*)(hbf + (size_t)d * HH);
    char* hsrow = (char*)sXhs + row*256;
    char* hdrow = (char*)sXhd + row*256;
    const int swz = (row & 7) << 4;
    #pragma unroll
    for (int c = 0; c < 4; ++c){
      int ch = q + c*4;                       // 0..15
      *(uint4*)(hsrow + ((ch*16) ^ swz)) = hs[ch];
    }
    #pragma unroll
    for (int c = 0; c < 4; ++c){
      int ch = q + c*4;
      *(uint4*)(hdrow + ((ch*16) ^ swz)) = hd[ch];
    }
    // tail: 32 cols = [ef(16) | nrm | zeros]; lane q covers cols q*8..q*8+7
    {
      float f[8];
      #pragma unroll
      for (int j = 0; j < 8; ++j) f[j] = 0.f;
      if (q < 2){
        const float* efp = ef + (size_t)eid * 16 + q*8;
        #pragma unroll
        for (int j = 0; j < 8; ++j) f[j] = efp[j];
      } else if (q == 2){
        f[0] = s_cdn[row].w;
      }
      uint4 v;
      v.x = f2bf(f[0]) | ((unsigned)f2bf(f[1]) << 16);
      v.y = f2bf(f[2]) | ((unsigned)f2bf(f[3]) << 16);
      v.z = f2bf(f[4]) | ((unsigned)f2bf(f[5]) << 16);
      v.w = f2bf(f[6]) | ((unsigned)f2bf(f[7]) << 16);
      *(uint4*)((char*)sXtail + row*64 + q*16) = v;
    }
  }

  u16* M1 = sXhs + R * 128;        // wave's own 16 rows (4KB), dead after ew1
  u16* Mb = sXhd + R * 128;

  f32x4 acc[8];
  mm_tile<4, 8, 256, true,  true >(sXhs,  R, ew1p,            eb1, 128, acc);  // K 0..127
  mm_tile<4, 8, 256, false, true >(sXhd,  R, ew1p + 4*8*512,  nullptr, 128, acc); // K 128..255
  mm_tile<1, 8,  64, false, false>(sXtail, R, ew1p + 8*8*512, nullptr, 128, acc); // K 256..287
  silu_store<8>(acc, M1, 0);                           // M1 = wave-local rows 0..15

  mm_tile<4, 8, 256, true, true>(M1, 0, ew2p, eb2, 128, acc); // silu(.) @ ew2 + eb2
  // m: silu, segmented-reduce over sorted rows, flush atomics; bf16 copy to Mb for cw1
  {
    const int rb = (lane >> 4) << 2;                  // local row base
    float run[8];
    #pragma unroll
    for (int cb = 0; cb < 8; ++cb) run[cb] = 0.f;
    #pragma unroll
    for (int j = 0; j < 4; ++j){
      int grow = R + rb + j;
      int src = s_src[grow];
      bool flush = (j == 3) || (s_src[grow + 1] != src);
      #pragma unroll
      for (int cb = 0; cb < 8; ++cb){
        int col = cb*16 + (lane & 15);
        float m = fsilu(acc[cb][j]);
        run[cb] += m;
        *(u16*)((char*)Mb + (rb + j)*256 + ((col*2) ^ (((rb + j) & 7) << 4))) = f2bf(m);
      }
      if (flush){
        #pragma unroll
        for (int cb = 0; cb < 8; ++cb){
          int col = cb*16 + (lane & 15);
          atomicAdd(&agg[(size_t)src * HH + col], run[cb]);
          run[cb] = 0.f;
        }
      }
    }
  }

  mm_tile<4, 8, 256, true, true>(Mb, 0, cw1p, cb1, 128, acc);  // m @ cw1 + cb1
  silu_store<8>(acc, M1, 0);                           // C1 overwrites M1 (own slice)

  f32x4 a4[1];
  mm_tile<4, 1, 256, true, true>(M1, 0, cw2p, cb2, 3, a4);     // silu(.) @ cw2 + cb2
  {
    int col = lane & 15;
    if (col < 3){
      const int rb = (lane >> 4) << 2;
      float run = 0.f;
      #pragma unroll
      for (int j = 0; j < 4; ++j){
        int grow = R + rb + j;
        float4 cdn = s_cdn[grow];
        float cdv = (col == 0) ? cdn.x : ((col == 1) ? cdn.y : cdn.z);
        run += cdv * a4[0][j];
        int src = s_src[grow];
        if (j == 3 || s_src[grow + 1] != src){
          atomicAdd(&acc_ct[(size_t)src * 3 + col], run);
          run = 0.f;
        }
      }
    }
  }
}

// ---------------- node kernel ----------------
// 64 nodes/block, 4 waves x 16 rows. Xn = [h | agg] bf16, [64][256] (512B rows).
__global__ __launch_bounds__(256) void node_kernel(
    float* __restrict__ coords, float* __restrict__ hf, u16* __restrict__ hbf,
    const float* __restrict__ agg, const float* __restrict__ acc_ct, const int* __restrict__ row_start,
    const float* __restrict__ nodes,
    const u16* __restrict__ vw1p, const u16* __restrict__ vw2p,
    const u16* __restrict__ nw1p, const u16* __restrict__ nw2p,
    const float* __restrict__ vb1, const float* __restrict__ vb2,
    const float* __restrict__ nb1, const float* __restrict__ nb2){
  __shared__ __align__(16) u16 sXn[64 * 256];
  __shared__ __align__(16) u16 sV[64 * 128];
  __shared__ float s_vt[64];

  const int tid = threadIdx.x, wid = tid >> 6, lane = tid & 63;
  const int R = wid * 16;
  const int g0 = blockIdx.x * 64;

  // stage Xn
  {
    int row = R + (lane >> 2), q = lane & 3, g = g0 + row;
    #pragma unroll
    for (int c = 0; c < 8; ++c){
      int col8 = q*64 + c*8;
      uint4 v = {0, 0, 0, 0};
      if (g < NN){
        if (col8 < 128) v = ((const uint4*)(hbf + (size_t)g * HH))[col8 >> 3];
        else {
          const float* ap = agg + (size_t)g * HH + (col8 - 128);
          float4 a0 = *(const float4*)ap;
          float4 a1 = *(const float4*)(ap + 4);
          v.x = f2bf(a0.x) | ((unsigned)f2bf(a0.y) << 16);
          v.y = f2bf(a0.z) | ((unsigned)f2bf(a0.w) << 16);
          v.z = f2bf(a1.x) | ((unsigned)f2bf(a1.y) << 16);
          v.w = f2bf(a1.z) | ((unsigned)f2bf(a1.w) << 16);
        }
      }
      *(uint4*)((char*)sXn + row*512 + ((col8*2) ^ ((row & 7) << 4))) = v;
    }
  }

  f32x4 acc[8];
  mm_tile<4, 8, 512, true, true>(sXn, R, vw1p, vb1, 128, acc);  // h @ vw1 (K=128 of 256)
  silu_store<8>(acc, sV, R);
  f32x4 a1[1];
  mm_tile<4, 1, 256, true, true>(sV, R, vw2p, vb2, 1, a1);      // @ vw2 -> scalar
  if ((lane & 15) == 0){
    #pragma unroll
    for (int j = 0; j < 4; ++j) s_vt[R + ((lane >> 4) << 2) + j] = a1[0][j];
  }
  // coords update (per-wave own rows)
  if (lane < 16){
    int row = R + lane, g = g0 + row;
    if (g < NN){
      float cn = (float)(row_start[g + 1] - row_start[g]);
      if (cn < 1.f) cn = 1.f;
      float vt = s_vt[row];
      #pragma unroll
      for (int c = 0; c < 3; ++c){
        float val = coords[g*3 + c] + acc_ct[g*3 + c] / cn + vt * nodes[(size_t)g*22 + 3 + c];
        coords[g*3 + c] = val;
      }
    }
  }

  mm_tile<8, 8, 512, true, true>(sXn, R, nw1p, nb1, 128, acc);  // [h|agg] @ nw1 (K=256)
  silu_store<8>(acc, sV, R);
  mm_tile<4, 8, 256, true, true>(sV, R, nw2p, nb2, 128, acc);   // @ nw2
  {
    #pragma unroll
    for (int cb = 0; cb < 8; ++cb){
      int col = cb*16 + (lane & 15);
      #pragma unroll
      for (int j = 0; j < 4; ++j){
        int row = R + ((lane >> 4) << 2) + j, g = g0 + row;
        if (g < NN){
          size_t off = (size_t)g * HH + col;
          float h = acc[cb][j] + hf[off];
          hf[off] = h;
          hbf[off] = f2bf(h);
        }
      }
    }
  }
}

// ---------------- host ----------------
extern "C" void kernel_launch(void* const* d_in, const int* in_sizes, int n_in,
                              void* d_out, int out_size, void* d_ws, size_t ws_size,
                              hipStream_t stream){
  const float* nodes = (const float*)d_in[0];
  const int*   eidx  = (const int*)d_in[1];
  const float* ef    = (const float*)d_in[2];
  const float* emb_w = (const float*)d_in[3];
  const float* emb_b = (const float*)d_in[4];
  const float* ew1 = (const float*)d_in[5];
  const float* eb1 = (const float*)d_in[6];
  const float* ew2 = (const float*)d_in[7];
  const float* eb2 = (const float*)d_in[8];
  const float* cw1 = (const float*)d_in[9];
  const float* cb1 = (const float*)d_in[10];
  const float* cw2 = (const float*)d_in[11];
  const float* cb2 = (const float*)d_in[12];
  const float* vw1 = (const float*)d_in[13];
  const float* vb1 = (const float*)d_in[14];
  const float* vw2 = (const float*)d_in[15];
  const float* vb2 = (const float*)d_in[16];
  const float* nw1 = (const float*)d_in[17];
  const float* nb1 = (const float*)d_in[18];
  const float* nw2 = (const float*)d_in[19];
  const float* nb2 = (const float*)d_in[20];

  // workspace budget ~77 MB; clean no-op if harness gives less (diagnosable absmax fail)
  constexpr size_t WS_NEEDED = 78u * 1024u * 1024u;
  if (ws_size < WS_NEEDED) return;

  char* ws = (char*)d_ws;
  size_t off = 0;
  auto alloc = [&](size_t bytes){ void* p = ws + off; off += (bytes + 255) & ~(size_t)255; return p; };
  float* coords   = (float*)alloc((size_t)NN * 3 * 4);
  float* hf       = (float*)alloc((size_t)NN * HH * 4);
  u16*   hbf      = (u16*)  alloc((size_t)NN * HH * 2);
  float* agg      = (float*)alloc((size_t)NN * 131 * 4);   // agg[N][128] + acc_ct[N][3]
  float* acc_ct   = agg + (size_t)NN * HH;
  int*   cnt_i    = (int*)  alloc((size_t)NN * 4);
  int*   row_start= (int*)  alloc((size_t)(NN + 1) * 4);
  int*   fill     = (int*)  alloc((size_t)NN * 4);
  int2*  sd_sorted= (int2*) alloc((size_t)EE * 8);
  int*   eid_sorted=(int*)  alloc((size_t)EE * 4);

  // packed weights (bf16 fragment order), per layer
  constexpr int O_EW1 = 0;
  constexpr int O_EW2 = O_EW1 + 9*8*512;
  constexpr int O_CW1 = O_EW2 + 4*8*512;
  constexpr int O_CW2 = O_CW1 + 4*8*512;
  constexpr int O_VW1 = O_CW2 + 4*1*512;
  constexpr int O_VW2 = O_VW1 + 4*8*512;
  constexpr int O_NW1 = O_VW2 + 4*1*512;
  constexpr int O_NW2 = O_NW1 + 8*8*512;
  constexpr int LAYER_PACK = O_NW2 + 4*8*512;
  u16* packs = (u16*)alloc((size_t)LAYER_PACK * 4 * 2);

  PackArgs pa;
  for (int l = 0; l < 4; ++l){
    u16* base = packs + (size_t)l * LAYER_PACK;
    int i = l * 8;
    pa.d[i+0] = { ew1 + (size_t)l*273*128, base + O_EW1, 273, 128, 8, 9, 1 };
    pa.d[i+1] = { ew2 + (size_t)l*128*128, base + O_EW2, 128, 128, 8, 4, 0 };
    pa.d[i+2] = { cw1 + (size_t)l*128*128, base + O_CW1, 128, 128, 8, 4, 0 };
    pa.d[i+3] = { cw2 + (size_t)l*128*3,   base + O_CW2, 128,   3, 1, 4, 0 };
    pa.d[i+4] = { vw1 + (size_t)l*128*128, base + O_VW1, 128, 128, 8, 4, 0 };
    pa.d[i+5] = { vw2 + (size_t)l*128*1,   base + O_VW2, 128,   1, 1, 4, 0 };
    pa.d[i+6] = { nw1 + (size_t)l*256*128, base + O_NW1, 256, 128, 8, 8, 0 };
    pa.d[i+7] = { nw2 + (size_t)l*128*128, base + O_NW2, 128, 128, 8, 4, 0 };
  }

  pack_kernel<<<32, 256, 0, stream>>>(pa);
  embed_kernel<<<(NN*4 + 255)/256, 256, 0, stream>>>(nodes, emb_w, emb_b, hf, hbf, coords);
  hipMemsetAsync(cnt_i, 0, (size_t)NN * 4, stream);
  count_kernel<<<(EE + 255)/256, 256, 0, stream>>>(eidx, cnt_i);
  scan_kernel<<<1, 256, 0, stream>>>(cnt_i, row_start, fill);
  scatter_kernel<<<(EE + 255)/256, 256, 0, stream>>>(eidx, eidx + EE, fill, sd_sorted, eid_sorted);

  for (int l = 0; l < 4; ++l){
    hipMemsetAsync(agg, 0, (size_t)NN * 131 * 4, stream);
    u16* base = packs + (size_t)l * LAYER_PACK;
    edge_kernel<<<EE/64, 256, 0, stream>>>(coords, hbf, ef, sd_sorted, eid_sorted,
        base + O_EW1, base + O_EW2, base + O_CW1, base + O_CW2,
        eb1 + l*128, eb2 + l*128, cb1 + l*128, cb2 + l*3, agg, acc_ct);
    node_kernel<<<(NN + 63)/64, 256, 0, stream>>>(coords, hf, hbf, agg, acc_ct, row_start, nodes,
        base + O_VW1, base + O_VW2, base + O_NW1, base + O_NW2,
        vb1 + l*128, vb2 + l, nb1 + l*128, nb2 + l*128);
  }

  hipMemcpyAsync(d_out, coords, (size_t)NN * 3 * 4, hipMemcpyDeviceToDevice, stream);
}

// Round 6
// 2216.744 us; speedup vs baseline: 1.2153x; 1.2153x over previous
//
#include <hip/hip_runtime.h>

constexpr int NN = 50000;
constexpr int EE = 800000;
constexpr int HH = 128;

typedef __attribute__((ext_vector_type(8))) __bf16 bfv8;
typedef __attribute__((ext_vector_type(4))) float f32x4;
typedef unsigned short u16;

__device__ __forceinline__ u16 f2bf(float x){
  unsigned u = __builtin_bit_cast(unsigned, x);
  u = u + 0x7fffu + ((u >> 16) & 1u);
  return (u16)(u >> 16);
}
// fast silu: v_rcp instead of precise-div sequence (no fast-math in harness)
__device__ __forceinline__ float fsilu(float x){
  return x * __builtin_amdgcn_rcpf(1.f + __expf(-x));
}

// A is LDS, row-major RB bytes/row, XOR-swizzled: element byte col c stored at c ^ ((row&7)<<4).
// B is packed fragment-order global: frag unit index (ks*CB+cb)*64 + lane, 8 bf16 each.
// B loads are software-pipelined with a depth-D rotating register window so
// ~2-3 K-steps of global loads stay in flight behind the MFMAs (round-4 compiler
// kept only 1 K-step in flight -> vmcnt-latency-bound, VGPR_Count 80).
template<int KSTEPS, int CB, int RB>
__device__ __forceinline__ void mm_tile(const u16* A, int Rbase, const u16* __restrict__ Bp,
                                        const float* __restrict__ bias, int NB, f32x4* acc){
  const int lane = threadIdx.x & 63;
  const int arow = Rbase + (lane & 15);
  const char* abase = (const char*)A + arow * RB;
  const int kb = (lane >> 4) * 16;          // byte offset of this lane-group's 8 k-elems
  const int swz = (arow & 7) << 4;
  const bfv8* __restrict__ bq = (const bfv8*)Bp + lane;

  constexpr int D = (CB >= 8) ? 3 : (KSTEPS < 4 ? KSTEPS : 4);
  bfv8 bw[D][CB];
  #pragma unroll
  for (int p = 0; p < (D < KSTEPS ? D : KSTEPS); ++p){
    #pragma unroll
    for (int cb = 0; cb < CB; ++cb) bw[p][cb] = bq[(p*CB + cb) * 64];
  }
  #pragma unroll
  for (int cb = 0; cb < CB; ++cb){
    int col = cb*16 + (lane & 15);
    float b = (col < NB) ? bias[col] : 0.f;
    acc[cb] = (f32x4){b, b, b, b};
  }
  #pragma unroll
  for (int ks = 0; ks < KSTEPS; ++ks){
    bfv8 a = *(const bfv8*)(abase + ((ks*64 + kb) ^ swz));
    #pragma unroll
    for (int cb = 0; cb < CB; ++cb)
      acc[cb] = __builtin_amdgcn_mfma_f32_16x16x32_bf16(a, bw[ks % D][cb], acc[cb], 0, 0, 0);
    if (ks + D < KSTEPS){
      #pragma unroll
      for (int cb = 0; cb < CB; ++cb) bw[ks % D][cb] = bq[((ks + D)*CB + cb) * 64];
    }
  }
}

// silu(acc) -> bf16 into LDS (256B rows, swizzled)
template<int CB>
__device__ __forceinline__ void silu_store(const f32x4* acc, u16* dst, int Rbase){
  const int lane = threadIdx.x & 63;
  #pragma unroll
  for (int cb = 0; cb < CB; ++cb){
    #pragma unroll
    for (int j = 0; j < 4; ++j){
      int row = Rbase + ((lane >> 4) << 2) + j;
      int col = cb*16 + (lane & 15);
      float s = fsilu(acc[cb][j]);
      *(u16*)((char*)dst + row*256 + ((col*2) ^ ((row & 7) << 4))) = f2bf(s);
    }
  }
}

// ---------------- weight packing ----------------
// remap==1 (ew1): X column order is [h_s(256) | ef(16)@256..271 | nrm@272 | pad]
// while source ew1 rows are [h(256) | nrm@256 | ef@257..272].
struct PackDesc { const float* src; u16* dst; int K; int Nc; int CB; int ksteps; int remap; };
struct PackArgs { PackDesc d[32]; };

__global__ __launch_bounds__(256) void pack_kernel(PackArgs pa){
  PackDesc d = pa.d[blockIdx.x];
  int total = d.ksteps * d.CB * 512;
  for (int p = threadIdx.x; p < total; p += 256){
    int j = p & 7, lane = (p >> 3) & 63, cbk = p >> 9;
    int cb = cbk % d.CB, ks = cbk / d.CB;
    int k = ks*32 + ((lane >> 4) * 8) + j;
    int col = cb*16 + (lane & 15);
    int kk = k;
    if (d.remap && k >= 256) kk = (k < 272) ? (k + 1) : ((k == 272) ? 256 : 0x7fffffff);
    float v = (kk < d.K && col < d.Nc) ? d.src[(size_t)kk * d.Nc + col] : 0.f;
    d.dst[p] = f2bf(v);
  }
}

// ---------------- embedding + coords init ----------------
__global__ __launch_bounds__(256) void embed_kernel(const float* __restrict__ nodes,
    const float* __restrict__ emb_w, const float* __restrict__ emb_b,
    float* __restrict__ hf, u16* __restrict__ hbf, float* __restrict__ coords){
  int t = blockIdx.x * 256 + threadIdx.x;
  int g = t >> 2, q = t & 3;
  if (g >= NN) return;
  const float* x = nodes + (size_t)g * 22;
  float acc[32];
  #pragma unroll
  for (int c = 0; c < 32; ++c) acc[c] = emb_b[q*32 + c];
  for (int k = 0; k < 16; ++k){
    float f = x[6 + k];
    const float* wr = emb_w + k*128 + q*32;
    #pragma unroll
    for (int c = 0; c < 32; ++c) acc[c] += f * wr[c];
  }
  size_t off = (size_t)g * HH + q*32;
  #pragma unroll
  for (int c = 0; c < 32; ++c){ hf[off + c] = acc[c]; hbf[off + c] = f2bf(acc[c]); }
  if (q == 0){
    coords[g*3+0] = x[0]; coords[g*3+1] = x[1]; coords[g*3+2] = x[2];
  }
}

// ---------------- CSR build (once per launch) ----------------
__global__ __launch_bounds__(256) void count_kernel(const int* __restrict__ esrc, int* __restrict__ cnt_i){
  int e = blockIdx.x * 256 + threadIdx.x;
  if (e < EE) atomicAdd(&cnt_i[esrc[e]], 1);
}

__global__ __launch_bounds__(256) void scan_kernel(const int* __restrict__ cnt_i,
    int* __restrict__ row_start, int* __restrict__ fill){
  __shared__ int part[256];
  int t = threadIdx.x;
  int lo = t * 196, hi = lo + 196;
  if (lo > NN) lo = NN;
  if (hi > NN) hi = NN;
  int s = 0;
  for (int i = lo; i < hi; ++i) s += cnt_i[i];
  part[t] = s; __syncthreads();
  for (int d = 1; d < 256; d <<= 1){
    int v = (t >= d) ? part[t-d] : 0;
    __syncthreads();
    part[t] += v;
    __syncthreads();
  }
  int run = part[t] - s;             // exclusive prefix
  for (int i = lo; i < hi; ++i){ row_start[i] = run; fill[i] = run; run += cnt_i[i]; }
  if (t == 255) row_start[NN] = run;
}

__global__ __launch_bounds__(256) void scatter_kernel(const int* __restrict__ esrc,
    const int* __restrict__ edst, int* __restrict__ fill,
    int2* __restrict__ sd_sorted, int* __restrict__ eid_sorted){
  int e = blockIdx.x * 256 + threadIdx.x;
  if (e < EE){
    int s = esrc[e];
    int pos = atomicAdd(&fill[s], 1);
    sd_sorted[pos] = make_int2(s, edst[e]);
    eid_sorted[pos] = e;
  }
}

// ---------------- edge kernel ----------------
// 64 sorted edges/block, 4 independent waves x 16 rows (no __syncthreads).
// X tile: [64][320] u16 (640B rows; logical K = 273 laid out [h_s|h_d|ef|nrm]).
// Each wave's M1/Mb scratch aliases its own 10240B slice of sX.
__global__ __launch_bounds__(256, 3) void edge_kernel(
    const float* __restrict__ coords, const u16* __restrict__ hbf, const float* __restrict__ ef,
    const int2* __restrict__ sd_sorted, const int* __restrict__ eid_sorted,
    const u16* __restrict__ ew1p, const u16* __restrict__ ew2p,
    const u16* __restrict__ cw1p, const u16* __restrict__ cw2p,
    const float* __restrict__ eb1, const float* __restrict__ eb2,
    const float* __restrict__ cb1, const float* __restrict__ cb2,
    float* __restrict__ agg, float* __restrict__ acc_ct){
  __shared__ u16 sX[64 * 320];
  __shared__ float4 s_cdn[64];
  __shared__ int s_src[64];
  __shared__ int s_dst[64];
  __shared__ int s_eid[64];

  const int tid = threadIdx.x, wid = tid >> 6, lane = tid & 63;
  const int R = wid * 16;
  const int e0 = blockIdx.x * 64;

  // Phase A: per-edge scalars (each wave fills its own 16 rows)
  if (lane < 16){
    int row = R + lane;
    int e = e0 + row;
    int2 sd = sd_sorted[e];
    float cx = coords[sd.x*3+0] - coords[sd.y*3+0];
    float cy = coords[sd.x*3+1] - coords[sd.y*3+1];
    float cz = coords[sd.x*3+2] - coords[sd.y*3+2];
    float nrm = sqrtf(cx*cx + cy*cy + cz*cz);
    s_cdn[row] = make_float4(cx, cy, cz, nrm);
    s_src[row] = sd.x; s_dst[row] = sd.y; s_eid[row] = eid_sorted[e];
  }
  // Phase B: stage X = [h[s](128) | h[d](128) | ef(16) | nrm | pad] with
  // wave-uniform region per iteration (4 lanes/row; chunk = q + 4c).
  {
    int row = R + (lane >> 2), q = lane & 3;
    int s = s_src[row], d = s_dst[row], eid = s_eid[row];
    const uint4* hs = (const uint4*)(hbf + (size_t)s * HH);
    const uint4* hd = (const uint4*)(hbf + (size_t)d * HH);
    char* xrow = (char*)sX + row*640;
    const int swz = (row & 7) << 4;
    #pragma unroll
    for (int c = 0; c < 4; ++c){
      int ch = q + c*4;                       // 0..15
      uint4 v = hs[ch];
      *(uint4*)(xrow + ((ch*16) ^ swz)) = v;
    }
    #pragma unroll
    for (int c = 0; c < 4; ++c){
      int ch = q + c*4;
      uint4 v = hd[ch];
      *(uint4*)(xrow + ((256 + ch*16) ^ swz)) = v;
    }
    // tail: logical cols 256..287 = [ef(16) | nrm | zeros]; q covers 8 cols each
    {
      float f[8];
      #pragma unroll
      for (int j = 0; j < 8; ++j) f[j] = 0.f;
      if (q < 2){
        const float* efp = ef + (size_t)eid * 16 + q*8;
        #pragma unroll
        for (int j = 0; j < 8; ++j) f[j] = efp[j];
      } else if (q == 2){
        f[0] = s_cdn[row].w;
      }
      uint4 v;
      v.x = f2bf(f[0]) | ((unsigned)f2bf(f[1]) << 16);
      v.y = f2bf(f[2]) | ((unsigned)f2bf(f[3]) << 16);
      v.z = f2bf(f[4]) | ((unsigned)f2bf(f[5]) << 16);
      v.w = f2bf(f[6]) | ((unsigned)f2bf(f[7]) << 16);
      *(uint4*)(xrow + ((512 + q*16) ^ swz)) = v;
    }
  }

  u16* wb = sX + R * 320;          // this wave's 10240B slice
  u16* Mb = wb + 2048;             // byte offset 4096, 16 rows x 256B

  f32x4 acc[8];
  mm_tile<9, 8, 640>(sX, R, ew1p, eb1, 128, acc);     // x @ ew1 + eb1
  silu_store<8>(acc, wb, 0);                           // M1 = wave-local rows 0..15

  mm_tile<4, 8, 256>(wb, 0, ew2p, eb2, 128, acc);     // silu(.) @ ew2 + eb2
  // m: silu, segmented-reduce over sorted rows, flush atomics; bf16 copy to Mb for cw1
  {
    const int rb = (lane >> 4) << 2;                  // local row base
    float run[8];
    #pragma unroll
    for (int cb = 0; cb < 8; ++cb) run[cb] = 0.f;
    #pragma unroll
    for (int j = 0; j < 4; ++j){
      int grow = R + rb + j;
      int src = s_src[grow];
      bool flush = (j == 3) || (s_src[grow + 1] != src);
      #pragma unroll
      for (int cb = 0; cb < 8; ++cb){
        int col = cb*16 + (lane & 15);
        float m = fsilu(acc[cb][j]);
        run[cb] += m;
        *(u16*)((char*)Mb + (rb + j)*256 + ((col*2) ^ (((rb + j) & 7) << 4))) = f2bf(m);
      }
      if (flush){
        #pragma unroll
        for (int cb = 0; cb < 8; ++cb){
          int col = cb*16 + (lane & 15);
          atomicAdd(&agg[(size_t)src * HH + col], run[cb]);
          run[cb] = 0.f;
        }
      }
    }
  }

  mm_tile<4, 8, 256>(Mb, 0, cw1p, cb1, 128, acc);     // m @ cw1 + cb1
  silu_store<8>(acc, wb, 0);                           // C1 overwrites M1 (own slice)

  f32x4 a4[1];
  mm_tile<4, 1, 256>(wb, 0, cw2p, cb2, 3, a4);        // silu(.) @ cw2 + cb2 (cols 0..2)
  {
    int col = lane & 15;
    if (col < 3){
      const int rb = (lane >> 4) << 2;
      float run = 0.f;
      #pragma unroll
      for (int j = 0; j < 4; ++j){
        int grow = R + rb + j;
        float4 cdn = s_cdn[grow];
        float cdv = (col == 0) ? cdn.x : ((col == 1) ? cdn.y : cdn.z);
        run += cdv * a4[0][j];
        int src = s_src[grow];
        if (j == 3 || s_src[grow + 1] != src){
          atomicAdd(&acc_ct[(size_t)src * 3 + col], run);
          run = 0.f;
        }
      }
    }
  }
}

// ---------------- node kernel ----------------
// 64 nodes/block, 4 waves x 16 rows. Xn = [h | agg] bf16, [64][256] (512B rows).
__global__ __launch_bounds__(256, 3) void node_kernel(
    float* __restrict__ coords, float* __restrict__ hf, u16* __restrict__ hbf,
    const float* __restrict__ agg, const float* __restrict__ acc_ct, const int* __restrict__ row_start,
    const float* __restrict__ nodes,
    const u16* __restrict__ vw1p, const u16* __restrict__ vw2p,
    const u16* __restrict__ nw1p, const u16* __restrict__ nw2p,
    const float* __restrict__ vb1, const float* __restrict__ vb2,
    const float* __restrict__ nb1, const float* __restrict__ nb2){
  __shared__ u16 sXn[64 * 256];
  __shared__ u16 sV[64 * 128];
  __shared__ float s_vt[64];

  const int tid = threadIdx.x, wid = tid >> 6, lane = tid & 63;
  const int R = wid * 16;
  const int g0 = blockIdx.x * 64;

  // stage Xn
  {
    int row = R + (lane >> 2), q = lane & 3, g = g0 + row;
    #pragma unroll
    for (int c = 0; c < 8; ++c){
      int col8 = q*64 + c*8;
      uint4 v = {0, 0, 0, 0};
      if (g < NN){
        if (col8 < 128) v = ((const uint4*)(hbf + (size_t)g * HH))[col8 >> 3];
        else {
          const float* ap = agg + (size_t)g * HH + (col8 - 128);
          float4 a0 = *(const float4*)ap;
          float4 a1 = *(const float4*)(ap + 4);
          v.x = f2bf(a0.x) | ((unsigned)f2bf(a0.y) << 16);
          v.y = f2bf(a0.z) | ((unsigned)f2bf(a0.w) << 16);
          v.z = f2bf(a1.x) | ((unsigned)f2bf(a1.y) << 16);
          v.w = f2bf(a1.z) | ((unsigned)f2bf(a1.w) << 16);
        }
      }
      *(uint4*)((char*)sXn + row*512 + ((col8*2) ^ ((row & 7) << 4))) = v;
    }
  }

  f32x4 acc[8];
  mm_tile<4, 8, 512>(sXn, R, vw1p, vb1, 128, acc);    // h @ vw1 (K=128 of 256)
  silu_store<8>(acc, sV, R);
  f32x4 a1[1];
  mm_tile<4, 1, 256>(sV, R, vw2p, vb2, 1, a1);        // @ vw2 -> scalar
  if ((lane & 15) == 0){
    #pragma unroll
    for (int j = 0; j < 4; ++j) s_vt[R + ((lane >> 4) << 2) + j] = a1[0][j];
  }
  // coords update (per-wave own rows)
  if (lane < 16){
    int row = R + lane, g = g0 + row;
    if (g < NN){
      float cn = (float)(row_start[g + 1] - row_start[g]);
      if (cn < 1.f) cn = 1.f;
      float vt = s_vt[row];
      #pragma unroll
      for (int c = 0; c < 3; ++c){
        float val = coords[g*3 + c] + acc_ct[g*3 + c] / cn + vt * nodes[(size_t)g*22 + 3 + c];
        coords[g*3 + c] = val;
      }
    }
  }

  mm_tile<8, 8, 512>(sXn, R, nw1p, nb1, 128, acc);    // [h|agg] @ nw1 (K=256)
  silu_store<8>(acc, sV, R);
  mm_tile<4, 8, 256>(sV, R, nw2p, nb2, 128, acc);     // @ nw2
  {
    #pragma unroll
    for (int cb = 0; cb < 8; ++cb){
      int col = cb*16 + (lane & 15);
      #pragma unroll
      for (int j = 0; j < 4; ++j){
        int row = R + ((lane >> 4) << 2) + j, g = g0 + row;
        if (g < NN){
          size_t off = (size_t)g * HH + col;
          float h = acc[cb][j] + hf[off];
          hf[off] = h;
          hbf[off] = f2bf(h);
        }
      }
    }
  }
}

// ---------------- host ----------------
extern "C" void kernel_launch(void* const* d_in, const int* in_sizes, int n_in,
                              void* d_out, int out_size, void* d_ws, size_t ws_size,
                              hipStream_t stream){
  const float* nodes = (const float*)d_in[0];
  const int*   eidx  = (const int*)d_in[1];
  const float* ef    = (const float*)d_in[2];
  const float* emb_w = (const float*)d_in[3];
  const float* emb_b = (const float*)d_in[4];
  const float* ew1 = (const float*)d_in[5];
  const float* eb1 = (const float*)d_in[6];
  const float* ew2 = (const float*)d_in[7];
  const float* eb2 = (const float*)d_in[8];
  const float* cw1 = (const float*)d_in[9];
  const float* cb1 = (const float*)d_in[10];
  const float* cw2 = (const float*)d_in[11];
  const float* cb2 = (const float*)d_in[12];
  const float* vw1 = (const float*)d_in[13];
  const float* vb1 = (const float*)d_in[14];
  const float* vw2 = (const float*)d_in[15];
  const float* vb2 = (const float*)d_in[16];
  const float* nw1 = (const float*)d_in[17];
  const float* nb1 = (const float*)d_in[18];
  const float* nw2 = (const float*)d_in[19];
  const float* nb2 = (const float*)d_in[20];

  // workspace budget ~77 MB; clean no-op if harness gives less (diagnosable absmax fail)
  constexpr size_t WS_NEEDED = 78u * 1024u * 1024u;
  if (ws_size < WS_NEEDED) return;

  char* ws = (char*)d_ws;
  size_t off = 0;
  auto alloc = [&](size_t bytes){ void* p = ws + off; off += (bytes + 255) & ~(size_t)255; return p; };
  float* coords   = (float*)alloc((size_t)NN * 3 * 4);
  float* hf       = (float*)alloc((size_t)NN * HH * 4);
  u16*   hbf      = (u16*)  alloc((size_t)NN * HH * 2);
  float* agg      = (float*)alloc((size_t)NN * 131 * 4);   // agg[N][128] + acc_ct[N][3]
  float* acc_ct   = agg + (size_t)NN * HH;
  int*   cnt_i    = (int*)  alloc((size_t)NN * 4);
  int*   row_start= (int*)  alloc((size_t)(NN + 1) * 4);
  int*   fill     = (int*)  alloc((size_t)NN * 4);
  int2*  sd_sorted= (int2*) alloc((size_t)EE * 8);
  int*   eid_sorted=(int*)  alloc((size_t)EE * 4);

  // packed weights (bf16 fragment order), per layer
  constexpr int O_EW1 = 0;
  constexpr int O_EW2 = O_EW1 + 9*8*512;
  constexpr int O_CW1 = O_EW2 + 4*8*512;
  constexpr int O_CW2 = O_CW1 + 4*8*512;
  constexpr int O_VW1 = O_CW2 + 4*1*512;
  constexpr int O_VW2 = O_VW1 + 4*8*512;
  constexpr int O_NW1 = O_VW2 + 4*1*512;
  constexpr int O_NW2 = O_NW1 + 8*8*512;
  constexpr int LAYER_PACK = O_NW2 + 4*8*512;
  u16* packs = (u16*)alloc((size_t)LAYER_PACK * 4 * 2);

  PackArgs pa;
  for (int l = 0; l < 4; ++l){
    u16* base = packs + (size_t)l * LAYER_PACK;
    int i = l * 8;
    pa.d[i+0] = { ew1 + (size_t)l*273*128, base + O_EW1, 273, 128, 8, 9, 1 };
    pa.d[i+1] = { ew2 + (size_t)l*128*128, base + O_EW2, 128, 128, 8, 4, 0 };
    pa.d[i+2] = { cw1 + (size_t)l*128*128, base + O_CW1, 128, 128, 8, 4, 0 };
    pa.d[i+3] = { cw2 + (size_t)l*128*3,   base + O_CW2, 128,   3, 1, 4, 0 };
    pa.d[i+4] = { vw1 + (size_t)l*128*128, base + O_VW1, 128, 128, 8, 4, 0 };
    pa.d[i+5] = { vw2 + (size_t)l*128*1,   base + O_VW2, 128,   1, 1, 4, 0 };
    pa.d[i+6] = { nw1 + (size_t)l*256*128, base + O_NW1, 256, 128, 8, 8, 0 };
    pa.d[i+7] = { nw2 + (size_t)l*128*128, base + O_NW2, 128, 128, 8, 4, 0 };
  }

  pack_kernel<<<32, 256, 0, stream>>>(pa);
  embed_kernel<<<(NN*4 + 255)/256, 256, 0, stream>>>(nodes, emb_w, emb_b, hf, hbf, coords);
  hipMemsetAsync(cnt_i, 0, (size_t)NN * 4, stream);
  count_kernel<<<(EE + 255)/256, 256, 0, stream>>>(eidx, cnt_i);
  scan_kernel<<<1, 256, 0, stream>>>(cnt_i, row_start, fill);
  scatter_kernel<<<(EE + 255)/256, 256, 0, stream>>>(eidx, eidx + EE, fill, sd_sorted, eid_sorted);

  for (int l = 0; l < 4; ++l){
    hipMemsetAsync(agg, 0, (size_t)NN * 131 * 4, stream);
    u16* base = packs + (size_t)l * LAYER_PACK;
    edge_kernel<<<EE/64, 256, 0, stream>>>(coords, hbf, ef, sd_sorted, eid_sorted,
        base + O_EW1, base + O_EW2, base + O_CW1, base + O_CW2,
        eb1 + l*128, eb2 + l*128, cb1 + l*128, cb2 + l*3, agg, acc_ct);
    node_kernel<<<(NN + 63)/64, 256, 0, stream>>>(coords, hf, hbf, agg, acc_ct, row_start, nodes,
        base + O_VW1, base + O_VW2, base + O_NW1, base + O_NW2,
        vb1 + l*128, vb2 + l, nb1 + l*128, nb2 + l*128);
  }

  hipMemcpyAsync(d_out, coords, (size_t)NN * 3 * 4, hipMemcpyDeviceToDevice, stream);
}